// Round 1
// baseline (66939.441 us; speedup 1.0000x reference)
//
#include <hip/hip_runtime.h>
#include <stdint.h>

// ---------------------------------------------------------------------------
// Persistent-grid GRU: 4 batch-groups x 16 batch, 64 WGs per group (1/CU).
// Weights LDS-resident as bf16 hi/lo MFMA fragments (fp32-accurate via 3-term
// split MFMA). Cross-WG sync via per-WG step-counter flags (agent scope).
// ---------------------------------------------------------------------------

#define T_STEPS 2048
#define B_SZ    64
#define D_SZ    256
#define H_SZ    512
#define NGROUP  4
#define NWG     64      // workgroups per group
#define MB      16      // batch rows per group
#define NCHUNK  24      // K = 768 = 24 chunks of 32
#define CPW     6       // chunks per wave (4 waves)

typedef __attribute__((ext_vector_type(8))) short  short8;
typedef __attribute__((ext_vector_type(4))) float  f32x4;

#define SMEM_BYTES (3*(2*NCHUNK*64*8)*2 + 4*64*4*4 + 32*4)   // 151680 B

__device__ __forceinline__ unsigned short f2bf(float v) {
  uint32_t u = __float_as_uint(v);
  uint32_t r = (u + 0x7fffu + ((u >> 16) & 1u)) >> 16;   // RTNE
  return (unsigned short)r;
}
__device__ __forceinline__ float bf2f(unsigned short h) {
  return __uint_as_float(((uint32_t)h) << 16);
}
__device__ __forceinline__ void splitf(float v, unsigned short& hi, unsigned short& lo) {
  hi = f2bf(v);
  lo = f2bf(v - bf2f(hi));
}

__global__ void __launch_bounds__(256)
gru_persistent(const float* __restrict__ x, const float* __restrict__ h0,
               const float* __restrict__ Wz, const float* __restrict__ bz,
               const float* __restrict__ Wr, const float* __restrict__ br,
               const float* __restrict__ Wh, const float* __restrict__ bh,
               float* __restrict__ out,
               uint32_t* zr_flags, uint32_t* h_flags,
               unsigned short* h_hi, unsigned short* h_lo,
               unsigned short* rh_hi, unsigned short* rh_lo,
               float* zbuf)
{
  extern __shared__ char smem[];
  unsigned short* wf1 = (unsigned short*)smem;            // [2][24][64][8] phase-1 weights (z or r slice)
  unsigned short* wf2 = wf1 + 2*NCHUNK*64*8;              // [2][24][64][8] phase-2 weights (h slice)
  unsigned short* af  = wf2 + 2*NCHUNK*64*8;              // [2][24][64][8] A fragments
  float* part  = (float*)(af + 2*NCHUNK*64*8);            // [4][64][4]
  float* bias1 = part + 4*64*4;                           // [16]
  float* bias2 = bias1 + 16;                              // [16]

  const int tid  = threadIdx.x;
  const int wv   = tid >> 6;
  const int lane = tid & 63;
  const int blk  = blockIdx.x;
  const int g    = blk >> 6;            // contiguous grouping: dispatch-order safe
  const int wid  = blk & 63;
  const int m0   = g * MB;
  const bool isZ = (wid < 32);
  const int c1   = (wid & 31) * 16;     // col base inside z-gate or r-gate [0,512)
  const int c2   = wid * 8;             // col base inside h-gate [0,512)
  const float* W1 = isZ ? Wz : Wr;

  // ---------------- init: stage weights into LDS in MFMA-fragment order ----
  {
    const int n  = lane & 15;
    const int kq = (lane >> 4) << 3;
    for (int ch = wv*CPW; ch < wv*CPW + CPW; ++ch) {
      unsigned short h8[8], l8[8];
      #pragma unroll
      for (int j = 0; j < 8; ++j) {
        int k = ch*32 + kq + j;
        splitf(W1[(size_t)k*H_SZ + c1 + n], h8[j], l8[j]);
      }
      #pragma unroll
      for (int j = 0; j < 8; ++j) {
        wf1[((0*NCHUNK+ch)*64 + lane)*8 + j] = h8[j];
        wf1[((1*NCHUNK+ch)*64 + lane)*8 + j] = l8[j];
      }
      #pragma unroll
      for (int j = 0; j < 8; ++j) {
        int k = ch*32 + kq + j;
        float v = (n < 8) ? Wh[(size_t)k*H_SZ + c2 + n] : 0.f;
        splitf(v, h8[j], l8[j]);
      }
      #pragma unroll
      for (int j = 0; j < 8; ++j) {
        wf2[((0*NCHUNK+ch)*64 + lane)*8 + j] = h8[j];
        wf2[((1*NCHUNK+ch)*64 + lane)*8 + j] = l8[j];
      }
    }
    if (tid < 16)       bias1[tid]    = isZ ? bz[c1 + tid] : br[c1 + tid];
    else if (tid < 32)  bias2[tid-16] = ((tid-16) < 8) ? bh[c2 + (tid-16)] : 0.f;
  }
  __syncthreads();

  int spin_cap = 1 << 20;   // degrade instead of deadlock

  #pragma unroll 1
  for (int t = 0; t < T_STEPS; ++t) {
    // ---- stage x_t fragments (chunks 0..7); independent of h, overlaps poll
    {
      const int m  = tid >> 4;
      const int kb = (tid & 15) << 4;   // 16 floats per thread
      const float* xr = x + ((size_t)t*B_SZ + m0 + m)*D_SZ + kb;
      #pragma unroll
      for (int hb = 0; hb < 2; ++hb) {
        const int k0 = kb + hb*8;
        short8 sh, sl;
        #pragma unroll
        for (int j = 0; j < 8; ++j) {
          unsigned short hi2, lo2; splitf(xr[hb*8 + j], hi2, lo2);
          sh[j] = (short)hi2; sl[j] = (short)lo2;
        }
        const int ch = k0 >> 5;
        const int l2 = (((k0 >> 3) & 3) << 4) | m;
        *(short8*)(af + ((0*NCHUNK+ch)*64 + l2)*8) = sh;
        *(short8*)(af + ((1*NCHUNK+ch)*64 + l2)*8) = sl;
      }
    }
    // ---- wait for h_{t-1}
    if (t > 0 && wv == 0) {
      uint32_t* p = h_flags + (g*NWG + lane)*16;
      const uint32_t tgt = (uint32_t)t;
      int guard = 0;
      for (;;) {
        uint32_t v = __hip_atomic_load(p, __ATOMIC_RELAXED, __HIP_MEMORY_SCOPE_AGENT);
        if (__ballot(v < tgt) == 0ull) break;
        if (++guard > spin_cap) { spin_cap = 256; break; }
        __builtin_amdgcn_s_sleep(2);
      }
      __threadfence();   // acquire: invalidate stale cached planes
    }
    __syncthreads();
    // ---- stage h-part of A (chunks 8..23)
    {
      const int m  = tid >> 4;
      const int b  = m0 + m;
      const int kb = (tid & 15) << 5;   // 32 elems per thread in [0,512)
      if (t == 0) {
        const float* hr = h0 + (size_t)b*H_SZ + kb;
        #pragma unroll
        for (int q = 0; q < 4; ++q) {
          const int k0 = kb + q*8;
          short8 sh, sl;
          #pragma unroll
          for (int j = 0; j < 8; ++j) {
            unsigned short hi2, lo2; splitf(hr[q*8 + j], hi2, lo2);
            sh[j] = (short)hi2; sl[j] = (short)lo2;
          }
          const int k  = 256 + k0;
          const int ch = k >> 5;
          const int l2 = (((k >> 3) & 3) << 4) | m;
          *(short8*)(af + ((0*NCHUNK+ch)*64 + l2)*8) = sh;
          *(short8*)(af + ((1*NCHUNK+ch)*64 + l2)*8) = sl;
        }
      } else {
        const unsigned short* ph = h_hi + (size_t)b*H_SZ + kb;
        const unsigned short* pl = h_lo + (size_t)b*H_SZ + kb;
        #pragma unroll
        for (int q = 0; q < 4; ++q) {
          const int k0 = kb + q*8;
          short8 sh = *(const short8*)(ph + q*8);
          short8 sl = *(const short8*)(pl + q*8);
          const int k  = 256 + k0;
          const int ch = k >> 5;
          const int l2 = (((k >> 3) & 3) << 4) | m;
          *(short8*)(af + ((0*NCHUNK+ch)*64 + l2)*8) = sh;
          *(short8*)(af + ((1*NCHUNK+ch)*64 + l2)*8) = sl;
        }
      }
    }
    __syncthreads();
    // ---- phase 1 MFMA: [16,768] @ [768,16] (z- or r-slice), 3-term split
    {
      f32x4 acc = {0.f, 0.f, 0.f, 0.f};
      const int base = wv * CPW;
      #pragma unroll
      for (int i = 0; i < CPW; ++i) {
        const int ch = base + i;
        short8 ah  = *(const short8*)(af  + ((0*NCHUNK+ch)*64 + lane)*8);
        short8 al  = *(const short8*)(af  + ((1*NCHUNK+ch)*64 + lane)*8);
        short8 bhv = *(const short8*)(wf1 + ((0*NCHUNK+ch)*64 + lane)*8);
        short8 blv = *(const short8*)(wf1 + ((1*NCHUNK+ch)*64 + lane)*8);
        acc = __builtin_amdgcn_mfma_f32_16x16x32_bf16(ah, bhv, acc, 0, 0, 0);
        acc = __builtin_amdgcn_mfma_f32_16x16x32_bf16(al, bhv, acc, 0, 0, 0);
        acc = __builtin_amdgcn_mfma_f32_16x16x32_bf16(ah, blv, acc, 0, 0, 0);
      }
      *(f32x4*)(part + (wv*64 + lane)*4) = acc;
    }
    __syncthreads();
    // ---- reduce K-split partials, activate, publish z or r*h
    {
      const int L = tid & 63, r = tid >> 6;
      float s = part[(0*64+L)*4+r] + part[(1*64+L)*4+r]
              + part[(2*64+L)*4+r] + part[(3*64+L)*4+r];
      const int m = ((L >> 4) << 2) + r;
      const int n = L & 15;
      const int b = m0 + m;
      s += bias1[n];
      float sg = 1.f / (1.f + __expf(-s));
      if (isZ) {
        zbuf[(size_t)b*H_SZ + c1 + n] = sg;
      } else {
        const int c = c1 + n;
        float hp = (t == 0) ? h0[(size_t)b*H_SZ + c]
                            : bf2f(h_hi[(size_t)b*H_SZ + c]) + bf2f(h_lo[(size_t)b*H_SZ + c]);
        float rh = sg * hp;
        unsigned short hi2, lo2; splitf(rh, hi2, lo2);
        rh_hi[(size_t)b*H_SZ + c] = hi2;
        rh_lo[(size_t)b*H_SZ + c] = lo2;
      }
    }
    __syncthreads();
    if (tid == 0) {
      __threadfence();   // release: push z/rh to coherent point
      __hip_atomic_store(zr_flags + (g*NWG + wid)*16, (uint32_t)(t+1),
                         __ATOMIC_RELAXED, __HIP_MEMORY_SCOPE_AGENT);
    }
    // ---- wait for all z/r of step t
    if (wv == 0) {
      uint32_t* p = zr_flags + (g*NWG + lane)*16;
      const uint32_t tgt = (uint32_t)(t + 1);
      int guard = 0;
      for (;;) {
        uint32_t v = __hip_atomic_load(p, __ATOMIC_RELAXED, __HIP_MEMORY_SCOPE_AGENT);
        if (__ballot(v < tgt) == 0ull) break;
        if (++guard > spin_cap) { spin_cap = 256; break; }
        __builtin_amdgcn_s_sleep(2);
      }
      __threadfence();
    }
    __syncthreads();
    // ---- stage rh-part of A (chunks 8..23)
    {
      const int m  = tid >> 4;
      const int b  = m0 + m;
      const int kb = (tid & 15) << 5;
      const unsigned short* ph = rh_hi + (size_t)b*H_SZ + kb;
      const unsigned short* pl = rh_lo + (size_t)b*H_SZ + kb;
      #pragma unroll
      for (int q = 0; q < 4; ++q) {
        const int k0 = kb + q*8;
        short8 sh = *(const short8*)(ph + q*8);
        short8 sl = *(const short8*)(pl + q*8);
        const int k  = 256 + k0;
        const int ch = k >> 5;
        const int l2 = (((k >> 3) & 3) << 4) | m;
        *(short8*)(af + ((0*NCHUNK+ch)*64 + l2)*8) = sh;
        *(short8*)(af + ((1*NCHUNK+ch)*64 + l2)*8) = sl;
      }
    }
    __syncthreads();
    // ---- phase 2 MFMA: [16,768] @ [768,8(+8 pad)] h-candidate slice
    {
      f32x4 acc = {0.f, 0.f, 0.f, 0.f};
      const int base = wv * CPW;
      #pragma unroll
      for (int i = 0; i < CPW; ++i) {
        const int ch = base + i;
        short8 ah  = *(const short8*)(af  + ((0*NCHUNK+ch)*64 + lane)*8);
        short8 al  = *(const short8*)(af  + ((1*NCHUNK+ch)*64 + lane)*8);
        short8 bhv = *(const short8*)(wf2 + ((0*NCHUNK+ch)*64 + lane)*8);
        short8 blv = *(const short8*)(wf2 + ((1*NCHUNK+ch)*64 + lane)*8);
        acc = __builtin_amdgcn_mfma_f32_16x16x32_bf16(ah, bhv, acc, 0, 0, 0);
        acc = __builtin_amdgcn_mfma_f32_16x16x32_bf16(al, bhv, acc, 0, 0, 0);
        acc = __builtin_amdgcn_mfma_f32_16x16x32_bf16(ah, blv, acc, 0, 0, 0);
      }
      *(f32x4*)(part + (wv*64 + lane)*4) = acc;
    }
    __syncthreads();
    // ---- reduce, tanh, h update, write history + publish h_t
    {
      const int L = tid & 63, r = tid >> 6;
      const int n = L & 15;
      if (n < 8) {
        float s = part[(0*64+L)*4+r] + part[(1*64+L)*4+r]
                + part[(2*64+L)*4+r] + part[(3*64+L)*4+r];
        const int m = ((L >> 4) << 2) + r;
        const int b = m0 + m;
        const int c = c2 + n;
        s += bias2[n];
        float e  = __expf(2.f * s);
        float ht = 1.f - 2.f / (e + 1.f);
        float hp = (t == 0) ? h0[(size_t)b*H_SZ + c]
                            : bf2f(h_hi[(size_t)b*H_SZ + c]) + bf2f(h_lo[(size_t)b*H_SZ + c]);
        float zv = zbuf[(size_t)b*H_SZ + c];
        float hn = (1.f - zv)*hp + zv*ht;
        out[((size_t)t*B_SZ + b)*H_SZ + c] = hn;
        unsigned short hi2, lo2; splitf(hn, hi2, lo2);
        h_hi[(size_t)b*H_SZ + c] = hi2;
        h_lo[(size_t)b*H_SZ + c] = lo2;
      }
    }
    __syncthreads();
    if (tid == 0) {
      __threadfence();   // release: push h_t to coherent point
      __hip_atomic_store(h_flags + (g*NWG + wid)*16, (uint32_t)(t+1),
                         __ATOMIC_RELAXED, __HIP_MEMORY_SCOPE_AGENT);
    }
  }
}

extern "C" void kernel_launch(void* const* d_in, const int* in_sizes, int n_in,
                              void* d_out, int out_size, void* d_ws, size_t ws_size,
                              hipStream_t stream) {
  const float* x  = (const float*)d_in[0];
  const float* h0 = (const float*)d_in[1];
  const float* Wz = (const float*)d_in[2];
  const float* bz = (const float*)d_in[3];
  const float* Wr = (const float*)d_in[4];
  const float* br = (const float*)d_in[5];
  const float* Wh = (const float*)d_in[6];
  const float* bh = (const float*)d_in[7];
  float* out = (float*)d_out;

  char* ws = (char*)d_ws;
  uint32_t*       zr_flags = (uint32_t*)(ws + 0);        // 4*64 flags, 64B stride
  uint32_t*       hf_flags = (uint32_t*)(ws + 16384);
  unsigned short* hhi      = (unsigned short*)(ws + 32768);    // [64][512] bf16
  unsigned short* hlo      = (unsigned short*)(ws + 98304);
  unsigned short* rhi      = (unsigned short*)(ws + 163840);
  unsigned short* rlo      = (unsigned short*)(ws + 229376);
  float*          zb       = (float*)(ws + 294912);            // [64][512] f32

  // zero only the flag region; everything else is written before it is read
  hipMemsetAsync(d_ws, 0, 32768, stream);
  hipFuncSetAttribute((const void*)gru_persistent,
                      hipFuncAttributeMaxDynamicSharedMemorySize, SMEM_BYTES);
  gru_persistent<<<dim3(NGROUP*NWG), dim3(256), SMEM_BYTES, stream>>>(
      x, h0, Wz, bz, Wr, br, Wh, bh, out,
      zr_flags, hf_flags, hhi, hlo, rhi, rlo, zb);
}

// Round 2
// 27545.602 us; speedup vs baseline: 2.4301x; 2.4301x over previous
//
#include <hip/hip_runtime.h>
#include <stdint.h>

// ---------------------------------------------------------------------------
// Persistent-grid GRU, fence-free cross-WG pipeline.
//  - 4 batch-groups x 16 rows, 64 WGs/group (256 WGs ~ 1/CU).
//  - Weights live in REGISTERS (step-invariant bf16 hi/lo MFMA B-fragments).
//  - Recurrent state transported as packed (bf16_hi<<16)|bf16_lo u32 planes
//    via agent-scope relaxed atomics (coherence-point ops, no L2 flushes).
//  - Per-group arrival counters (atomicAdd) + broadcast polls; NO
//    __threadfence anywhere.
// ---------------------------------------------------------------------------

#define T_STEPS 2048
#define B_SZ    64
#define D_SZ    256
#define H_SZ    512
#define NGROUP  4
#define NWG     64
#define MB      16
#define CPW     6     // K-chunks (of 32) per wave; 4 waves * 6 = 24 = K 768

typedef __attribute__((ext_vector_type(8))) short  short8;
typedef __attribute__((ext_vector_type(4))) float  f32x4;

__device__ __forceinline__ unsigned short f2bf(float v) {
  uint32_t u = __float_as_uint(v);
  return (unsigned short)((u + 0x7fffu + ((u >> 16) & 1u)) >> 16);   // RTNE
}
__device__ __forceinline__ float bf2f(unsigned short h) {
  return __uint_as_float(((uint32_t)h) << 16);
}
__device__ __forceinline__ void splitf(float v, short& hi, short& lo) {
  unsigned short h = f2bf(v);
  hi = (short)h;
  lo = (short)f2bf(v - bf2f(h));
}
__device__ __forceinline__ uint32_t packf(float v) {
  unsigned short h = f2bf(v);
  unsigned short l = f2bf(v - bf2f(h));
  return ((uint32_t)h << 16) | (uint32_t)l;
}
__device__ __forceinline__ float unpackf(uint32_t p) {
  return __uint_as_float(p & 0xffff0000u) + __uint_as_float(p << 16);
}

__device__ __forceinline__ uint32_t aload32(const uint32_t* p) {
  return __hip_atomic_load(p, __ATOMIC_RELAXED, __HIP_MEMORY_SCOPE_AGENT);
}
__device__ __forceinline__ unsigned long long aload64(const uint32_t* p) {
  return __hip_atomic_load((const unsigned long long*)p, __ATOMIC_RELAXED,
                           __HIP_MEMORY_SCOPE_AGENT);
}
__device__ __forceinline__ void astore32(uint32_t* p, uint32_t v) {
  __hip_atomic_store(p, v, __ATOMIC_RELAXED, __HIP_MEMORY_SCOPE_AGENT);
}

__device__ __forceinline__ void poll_ge(const uint32_t* p, uint32_t tgt, int& cap) {
  int guard = 0;
  for (;;) {
    if (aload32(p) >= tgt) break;
    if (++guard > cap) { cap = 256; break; }   // degrade, never deadlock
    __builtin_amdgcn_s_sleep(1);
  }
}

__global__ void __launch_bounds__(256, 1)
gru_persistent(const float* __restrict__ x, const float* __restrict__ h0,
               const float* __restrict__ Wz, const float* __restrict__ bz,
               const float* __restrict__ Wr, const float* __restrict__ br,
               const float* __restrict__ Wh, const float* __restrict__ bh,
               float* __restrict__ out,
               uint32_t* zr_ctr, uint32_t* h_ctr,
               uint32_t* h_pk, uint32_t* rh_pk, uint32_t* z_pk)
{
  __shared__ float partT[16 * 64];   // [kslice i][reg r][lane] transposed: conflict-free
  __shared__ float bias1s[16];
  __shared__ float bias2s[8];

  const int tid  = threadIdx.x;
  const int wv   = tid >> 6;
  const int lane = tid & 63;
  const int blk  = blockIdx.x;
  const int g    = blk >> 6;           // contiguous grouping: dispatch-order safe
  const int wid  = blk & 63;
  const int m0   = g * MB;
  const bool isZ = (wid < 32);
  const int c1   = (wid & 31) * 16;    // phase-1 column base (z or r gate)
  const int c2   = wid * 8;            // phase-2 column base (h gate)
  const float* W1 = isZ ? Wz : Wr;

  const int n     = lane & 15;         // MFMA fragment col / A-row-in-tile
  const int kq    = lane >> 4;         // k-quad
  const int bfrag = m0 + n;            // batch row this lane's A fragment holds
  const int m2    = kq * 4 + wv;       // C-layout row for this thread
  const int n2    = n;                 // C-layout col
  const int b2    = m0 + m2;

  uint32_t* my_zr = zr_ctr + g * 64;   // 256 B stride between groups
  uint32_t* my_h  = h_ctr  + g * 64;

  // ---- weights -> registers (B fragments, bf16 hi/lo; step-invariant) ----
  short8 w1h[CPW], w1l[CPW], w2h[CPW], w2l[CPW];
  #pragma unroll
  for (int i = 0; i < CPW; ++i) {
    const int ch = wv * CPW + i;
    #pragma unroll
    for (int j = 0; j < 8; ++j) {
      const int k = ch * 32 + kq * 8 + j;
      short hi, lo;
      splitf(W1[(size_t)k * H_SZ + c1 + n], hi, lo);
      w1h[i][j] = hi; w1l[i][j] = lo;
      float v = (n < 8) ? Wh[(size_t)k * H_SZ + c2 + n] : 0.f;
      splitf(v, hi, lo);
      w2h[i][j] = hi; w2l[i][j] = lo;
    }
  }
  if (tid < 16)      bias1s[tid] = isZ ? bz[c1 + tid] : br[c1 + tid];
  else if (tid < 24) bias2s[tid - 16] = bh[c2 + (tid - 16)];
  __syncthreads();

  // own recurrent column kept as exact f32 register chain
  float hreg = (n2 < 8) ? h0[(size_t)b2 * H_SZ + c2 + n2] : 0.f;

  int cap = 1 << 20;

  #pragma unroll 1
  for (int t = 0; t < T_STEPS; ++t) {
    short8 ah[CPW], al[CPW];

    // ---- x fragments (chunks 0..7): independent of h, issue before poll ----
    #pragma unroll
    for (int i = 0; i < CPW; ++i) {
      const int ch = wv * CPW + i;
      if (ch < 8) {
        const float* xp = x + ((size_t)t * B_SZ + bfrag) * D_SZ + ch * 32 + kq * 8;
        float4 f0 = *(const float4*)xp;
        float4 f1 = *(const float4*)(xp + 4);
        float f[8] = {f0.x, f0.y, f0.z, f0.w, f1.x, f1.y, f1.z, f1.w};
        #pragma unroll
        for (int j = 0; j < 8; ++j) { short hi, lo; splitf(f[j], hi, lo); ah[i][j] = hi; al[i][j] = lo; }
      }
    }

    // ---- wait for h_{t-1} (all waves poll; broadcast load, no barrier) ----
    if (t > 0) poll_ge(my_h, (uint32_t)t * NWG, cap);

    // early per-thread load: r-gate needs own h_{t-1}[b2, c1+n2]
    uint32_t hpu = 0; float hp0 = 0.f;
    if (!isZ) {
      if (t > 0) hpu = aload32(h_pk + (size_t)b2 * H_SZ + c1 + n2);
      else       hp0 = h0[(size_t)b2 * H_SZ + c1 + n2];
    }

    // ---- h fragments (chunks 8..23) straight into registers ----
    #pragma unroll
    for (int i = 0; i < CPW; ++i) {
      const int ch = wv * CPW + i;
      if (ch >= 8) {
        const int kh = ch * 32 - 256 + kq * 8;
        if (t > 0) {
          const uint32_t* hp = h_pk + (size_t)bfrag * H_SZ + kh;
          unsigned long long q0 = aload64(hp),     q1 = aload64(hp + 2);
          unsigned long long q2 = aload64(hp + 4), q3 = aload64(hp + 6);
          uint32_t u[8] = {(uint32_t)q0, (uint32_t)(q0 >> 32), (uint32_t)q1, (uint32_t)(q1 >> 32),
                           (uint32_t)q2, (uint32_t)(q2 >> 32), (uint32_t)q3, (uint32_t)(q3 >> 32)};
          #pragma unroll
          for (int j = 0; j < 8; ++j) { ah[i][j] = (short)(u[j] >> 16); al[i][j] = (short)(u[j] & 0xffffu); }
        } else {
          const float* hp = h0 + (size_t)bfrag * H_SZ + kh;
          float4 f0 = *(const float4*)hp;
          float4 f1 = *(const float4*)(hp + 4);
          float f[8] = {f0.x, f0.y, f0.z, f0.w, f1.x, f1.y, f1.z, f1.w};
          #pragma unroll
          for (int j = 0; j < 8; ++j) { short hi, lo; splitf(f[j], hi, lo); ah[i][j] = hi; al[i][j] = lo; }
        }
      }
    }

    // ---- phase-1 MFMA: [16,768] @ [768,16], 3-term hi/lo split ----
    {
      f32x4 acc = {0.f, 0.f, 0.f, 0.f};
      #pragma unroll
      for (int i = 0; i < CPW; ++i) {
        acc = __builtin_amdgcn_mfma_f32_16x16x32_bf16(ah[i], w1h[i], acc, 0, 0, 0);
        acc = __builtin_amdgcn_mfma_f32_16x16x32_bf16(al[i], w1h[i], acc, 0, 0, 0);
        acc = __builtin_amdgcn_mfma_f32_16x16x32_bf16(ah[i], w1l[i], acc, 0, 0, 0);
      }
      #pragma unroll
      for (int r = 0; r < 4; ++r) partT[(wv * 4 + r) * 64 + lane] = acc[r];
    }
    __syncthreads();

    // ---- reduce K-slices, activate, publish z / r*h (coherent stores) ----
    {
      float s = partT[(0 + wv) * 64 + lane] + partT[(4 + wv) * 64 + lane]
              + partT[(8 + wv) * 64 + lane] + partT[(12 + wv) * 64 + lane] + bias1s[n2];
      float sg = 1.f / (1.f + __expf(-s));
      if (isZ) {
        astore32(z_pk + (size_t)b2 * H_SZ + c1 + n2, __float_as_uint(sg));
      } else {
        float hp = (t > 0) ? unpackf(hpu) : hp0;
        astore32(rh_pk + (size_t)b2 * H_SZ + c1 + n2, packf(sg * hp));
      }
    }
    asm volatile("s_waitcnt vmcnt(0)" ::: "memory");  // stores complete at coherence point
    __syncthreads();
    if (tid == 0)
      __hip_atomic_fetch_add(my_zr, 1u, __ATOMIC_RELAXED, __HIP_MEMORY_SCOPE_AGENT);

    // ---- wait for all z / r*h of step t ----
    poll_ge(my_zr, (uint32_t)(t + 1) * NWG, cap);

    uint32_t zu = 0;
    if (n2 < 8) zu = aload32(z_pk + (size_t)b2 * H_SZ + c2 + n2);  // overlap with MFMA

    // ---- rh fragments (chunks 8..23); x chunks still in regs ----
    #pragma unroll
    for (int i = 0; i < CPW; ++i) {
      const int ch = wv * CPW + i;
      if (ch >= 8) {
        const int kh = ch * 32 - 256 + kq * 8;
        const uint32_t* rp = rh_pk + (size_t)bfrag * H_SZ + kh;
        unsigned long long q0 = aload64(rp),     q1 = aload64(rp + 2);
        unsigned long long q2 = aload64(rp + 4), q3 = aload64(rp + 6);
        uint32_t u[8] = {(uint32_t)q0, (uint32_t)(q0 >> 32), (uint32_t)q1, (uint32_t)(q1 >> 32),
                         (uint32_t)q2, (uint32_t)(q2 >> 32), (uint32_t)q3, (uint32_t)(q3 >> 32)};
        #pragma unroll
        for (int j = 0; j < 8; ++j) { ah[i][j] = (short)(u[j] >> 16); al[i][j] = (short)(u[j] & 0xffffu); }
      }
    }

    // ---- phase-2 MFMA: h-candidate slice (8 live cols, 8 zero-padded) ----
    {
      f32x4 acc = {0.f, 0.f, 0.f, 0.f};
      #pragma unroll
      for (int i = 0; i < CPW; ++i) {
        acc = __builtin_amdgcn_mfma_f32_16x16x32_bf16(ah[i], w2h[i], acc, 0, 0, 0);
        acc = __builtin_amdgcn_mfma_f32_16x16x32_bf16(al[i], w2h[i], acc, 0, 0, 0);
        acc = __builtin_amdgcn_mfma_f32_16x16x32_bf16(ah[i], w2l[i], acc, 0, 0, 0);
      }
      #pragma unroll
      for (int r = 0; r < 4; ++r) partT[(wv * 4 + r) * 64 + lane] = acc[r];
    }
    __syncthreads();

    // ---- reduce, tanh, h-update (exact f32 register chain), publish ----
    if (n2 < 8) {
      float s = partT[(0 + wv) * 64 + lane] + partT[(4 + wv) * 64 + lane]
              + partT[(8 + wv) * 64 + lane] + partT[(12 + wv) * 64 + lane] + bias2s[n2];
      float e  = __expf(2.f * s);
      float ht = 1.f - 2.f / (e + 1.f);
      float zf = __uint_as_float(zu);
      float hn = (1.f - zf) * hreg + zf * ht;
      hreg = hn;
      __builtin_nontemporal_store(hn, out + ((size_t)t * B_SZ + b2) * H_SZ + c2 + n2);
      astore32(h_pk + (size_t)b2 * H_SZ + c2 + n2, packf(hn));
    }
    asm volatile("s_waitcnt vmcnt(0)" ::: "memory");
    __syncthreads();
    if (tid == 0)
      __hip_atomic_fetch_add(my_h, 1u, __ATOMIC_RELAXED, __HIP_MEMORY_SCOPE_AGENT);
  }
}

extern "C" void kernel_launch(void* const* d_in, const int* in_sizes, int n_in,
                              void* d_out, int out_size, void* d_ws, size_t ws_size,
                              hipStream_t stream) {
  const float* x  = (const float*)d_in[0];
  const float* h0 = (const float*)d_in[1];
  const float* Wz = (const float*)d_in[2];
  const float* bz = (const float*)d_in[3];
  const float* Wr = (const float*)d_in[4];
  const float* br = (const float*)d_in[5];
  const float* Wh = (const float*)d_in[6];
  const float* bh = (const float*)d_in[7];
  float* out = (float*)d_out;

  char* ws = (char*)d_ws;
  uint32_t* zr_ctr = (uint32_t*)(ws + 0);        // per-group arrival counters
  uint32_t* h_ctr  = (uint32_t*)(ws + 16384);
  uint32_t* h_pk   = (uint32_t*)(ws + 32768);    // [64][512] packed bf16 hi|lo
  uint32_t* rh_pk  = (uint32_t*)(ws + 163840);
  uint32_t* z_pk   = (uint32_t*)(ws + 294912);   // [64][512] f32 bits

  // zero only the counters; data planes are written before they are read
  hipMemsetAsync(d_ws, 0, 32768, stream);
  gru_persistent<<<dim3(NGROUP * NWG), dim3(256), 0, stream>>>(
      x, h0, Wz, bz, Wr, br, Wh, bh, out,
      zr_ctr, h_ctr, h_pk, rh_pk, z_pk);
}